// Round 4
// baseline (8444.961 us; speedup 1.0000x reference)
//
#include <hip/hip_runtime.h>
#include <math.h>
#include <stdint.h>

typedef __attribute__((ext_vector_type(8))) short bf16x8;
typedef __attribute__((ext_vector_type(4))) float f32x4;

union BF8 { ushort u[8]; bf16x8 v; };

__device__ __forceinline__ void gll16(const void* g, void* l) {
  __builtin_amdgcn_global_load_lds(
      (const __attribute__((address_space(1))) uint32_t*)g,
      (__attribute__((address_space(3))) uint32_t*)l, 16, 0, 0);
}

__device__ __forceinline__ void split_bf(float x, ushort& h, ushort& lo) {
  uint b = __float_as_uint(x);
  h = (ushort)(b >> 16);
  float hf = __uint_as_float((uint)h << 16);
  lo = (ushort)(__float_as_uint(x - hf) >> 16);
}

#define EPI_SILU 0
#define EPI_GELU 1
#define EPI_LN   2
#define EPI_LN2  3
#define EPI_RES  4

// ---------------------------------------------------------------------------
// MFMA GEMM, block tile 128x256, 8 waves (2 row x 4 col), wave tile 64x64 as
// 4x4 fragments of v_mfma_f32_16x16x32_bf16, 3-term split-bf16.
// B pre-transposed hi/lo [N][K]. A hi/lo planes (or fp32 reg-split if AF32).
// Staging: fragment-gather global_load_lds (linear LDS dest, conflict-free
// lane*16B ds_read_b128).  Fused epilogues incl. LayerNorm over the 256-wide
// block and coalesced stores via per-wave padded LDS transpose.
// ---------------------------------------------------------------------------
template<int KSTEPS, int EPI, bool AF32>
__global__ __launch_bounds__(512, 4) void k_gemm(
    const void* __restrict__ A0, const ushort* __restrict__ Alo, int lda,
    int aoff_per_by,
    const ushort* __restrict__ Bhi, const ushort* __restrict__ Blo,
    const float* __restrict__ bias,
    const float* __restrict__ lnw, const float* __restrict__ lnb,
    const float* __restrict__ ln2w, const float* __restrict__ ln2b,
    const float* __restrict__ resid, const float* __restrict__ kmask,
    void* __restrict__ out0, ushort* __restrict__ out_lo, int ldo,
    float* __restrict__ out_xc) {
  constexpr int K = KSTEPS * 32;
  __shared__ __align__(16) ushort lds[24576];  // 48 KB
  const int tid = threadIdx.x;
  const int lane = tid & 63;
  const int w = tid >> 6;
  const int wr = w >> 2, wc = w & 3;
  const int row0 = blockIdx.x * 128;
  const int by = blockIdx.y;
  const int col0 = by * 256;
  const int lrow = lane & 15, lk8 = (lane >> 4) * 8;
  const int aoff = by * aoff_per_by;

  const ushort* Ahi = (const ushort*)A0;
  const float* Af = (const float*)A0;

  f32x4 acc[4][4];
#pragma unroll
  for (int i = 0; i < 4; ++i)
#pragma unroll
    for (int j = 0; j < 4; ++j) acc[i][j] = (f32x4){0.f, 0.f, 0.f, 0.f};

  auto stage = [&](int s) {
    if (AF32) {
      const ushort* bp = (w < 4) ? Bhi : Blo;
      const int pl = (w < 4) ? 0 : 1;
      const int rbb = (w & 3) * 4;
#pragma unroll
      for (int i = 0; i < 4; ++i) {
        int rb = rbb + i;
        gll16(bp + (size_t)(col0 + rb * 16 + lrow) * K + s * 32 + lk8,
              &lds[8192 + (pl * 16 + rb) * 512]);
      }
      int rb = tid >> 6;
      int fl = tid & 63;
      int frow = fl & 15, fk = (fl >> 4) * 8;
      const float* sp = Af + (size_t)(row0 + rb * 16 + frow) * lda + s * 32 + fk;
      float4 x0 = *(const float4*)sp;
      float4 x1 = *(const float4*)(sp + 4);
      float xs[8] = {x0.x, x0.y, x0.z, x0.w, x1.x, x1.y, x1.z, x1.w};
      BF8 h, l;
#pragma unroll
      for (int e = 0; e < 8; ++e) split_bf(xs[e], h.u[e], l.u[e]);
      *(bf16x8*)&lds[(0 * 8 + rb) * 512 + fl * 8] = h.v;
      *(bf16x8*)&lds[(1 * 8 + rb) * 512 + fl * 8] = l.v;
    } else {
      if (w < 2) {
        const ushort* ap = w ? Alo : Ahi;
#pragma unroll
        for (int i = 0; i < 8; ++i)
          gll16(ap + (size_t)(row0 + i * 16 + lrow) * lda + aoff + s * 32 + lk8,
                &lds[(w * 8 + i) * 512]);
      } else if (w < 6) {
        const int pl = (w - 2) >> 1;
        const ushort* bp = pl ? Blo : Bhi;
        const int rbb = ((w - 2) & 1) * 8;
#pragma unroll
        for (int i = 0; i < 8; ++i) {
          int rb = rbb + i;
          gll16(bp + (size_t)(col0 + rb * 16 + lrow) * K + s * 32 + lk8,
                &lds[8192 + (pl * 16 + rb) * 512]);
        }
      }
    }
  };

  stage(0);

#pragma unroll 1
  for (int s = 0; s < KSTEPS; ++s) {
    __syncthreads();  // staged data visible
    bf16x8 fa[4], fb[4], fc[4];
#pragma unroll
    for (int f = 0; f < 4; ++f) {
      fa[f] = *(const bf16x8*)&lds[(wr * 4 + f) * 512 + lane * 8];              // A hi
      fb[f] = *(const bf16x8*)&lds[8192 + (wc * 4 + f) * 512 + lane * 8];       // B hi
      fc[f] = *(const bf16x8*)&lds[8192 + (16 + wc * 4 + f) * 512 + lane * 8];  // B lo
    }
#pragma unroll
    for (int f = 0; f < 4; ++f)
#pragma unroll
      for (int g = 0; g < 4; ++g)
        acc[f][g] = __builtin_amdgcn_mfma_f32_16x16x32_bf16(fa[f], fb[g], acc[f][g], 0, 0, 0);
#pragma unroll
    for (int f = 0; f < 4; ++f)
#pragma unroll
      for (int g = 0; g < 4; ++g)
        acc[f][g] = __builtin_amdgcn_mfma_f32_16x16x32_bf16(fa[f], fc[g], acc[f][g], 0, 0, 0);
#pragma unroll
    for (int f = 0; f < 4; ++f)  // A lo (reuse fa regs)
      fa[f] = *(const bf16x8*)&lds[(8 + wr * 4 + f) * 512 + lane * 8];
    __syncthreads();  // all LDS reads done; safe to overwrite
    if (s + 1 < KSTEPS) stage(s + 1);
#pragma unroll
    for (int f = 0; f < 4; ++f)
#pragma unroll
      for (int g = 0; g < 4; ++g)
        acc[f][g] = __builtin_amdgcn_mfma_f32_16x16x32_bf16(fa[f], fb[g], acc[f][g], 0, 0, 0);
  }

  // ---------------- epilogue ----------------
  // C/D layout [m89]: col = lane&15 (+g*16), row = (lane>>4)*4 + r (+f*16)
  float* trw = (float*)((char*)lds + w * 4352);       // per-wave 16x68 f32
  float* st  = (float*)((char*)lds + 34816);          // [128][4][2] partials 1
  float* st2 = (float*)((char*)lds + 38912);          // [128][2] final stats2
  float* stB = (float*)((char*)lds + 39936);          // [128][4][2] partials 2

  float b4[4];
#pragma unroll
  for (int g = 0; g < 4; ++g) b4[g] = bias[col0 + wc * 64 + (lane & 15) + g * 16];

  float v[4][4][4];
#pragma unroll
  for (int f = 0; f < 4; ++f)
#pragma unroll
    for (int g = 0; g < 4; ++g)
#pragma unroll
      for (int r = 0; r < 4; ++r) v[f][g][r] = acc[f][g][r] + b4[g];

  if (EPI == EPI_LN2) {  // add residual (pre-LN)
#pragma unroll
    for (int f = 0; f < 4; ++f)
#pragma unroll
      for (int r = 0; r < 4; ++r) {
        size_t grow = row0 + wr * 64 + f * 16 + (lane >> 4) * 4 + r;
#pragma unroll
        for (int g = 0; g < 4; ++g)
          v[f][g][r] += resid[grow * 256 + wc * 64 + (lane & 15) + g * 16];
      }
  }

  float mu[4][4], rs[4][4];
  if (EPI == EPI_LN || EPI == EPI_LN2) {
#pragma unroll
    for (int f = 0; f < 4; ++f)
#pragma unroll
      for (int r = 0; r < 4; ++r) {
        float s1 = 0.f, s2 = 0.f;
#pragma unroll
        for (int g = 0; g < 4; ++g) { s1 += v[f][g][r]; s2 += v[f][g][r] * v[f][g][r]; }
#pragma unroll
        for (int m = 1; m < 16; m <<= 1) { s1 += __shfl_xor(s1, m, 64); s2 += __shfl_xor(s2, m, 64); }
        if ((lane & 15) == 0) {
          int rowl = wr * 64 + f * 16 + (lane >> 4) * 4 + r;
          st[(rowl * 4 + wc) * 2] = s1; st[(rowl * 4 + wc) * 2 + 1] = s2;
        }
      }
    __syncthreads();
#pragma unroll
    for (int f = 0; f < 4; ++f)
#pragma unroll
      for (int r = 0; r < 4; ++r) {
        int rowl = wr * 64 + f * 16 + (lane >> 4) * 4 + r;
        float s1 = 0.f, s2 = 0.f;
#pragma unroll
        for (int q = 0; q < 4; ++q) { s1 += st[(rowl * 4 + q) * 2]; s2 += st[(rowl * 4 + q) * 2 + 1]; }
        mu[f][r] = s1 * (1.f / 256.f);
        rs[f][r] = rsqrtf(s2 * (1.f / 256.f) - mu[f][r] * mu[f][r] + 1e-5f);
      }
  }

  if (EPI == EPI_LN) {
#pragma unroll
    for (int f = 0; f < 4; ++f)
#pragma unroll
      for (int g = 0; g < 4; ++g)
#pragma unroll
        for (int r = 0; r < 4; ++r) v[f][g][r] = (v[f][g][r] - mu[f][r]) * rs[f][r];
  }

  if (EPI == EPI_LN2) {
    float nw4[4], nb4[4];
#pragma unroll
    for (int g = 0; g < 4; ++g) {
      int c = wc * 64 + (lane & 15) + g * 16;
      nw4[g] = lnw[c]; nb4[g] = lnb[c];
    }
#pragma unroll
    for (int f = 0; f < 4; ++f)
#pragma unroll
      for (int g = 0; g < 4; ++g)
#pragma unroll
        for (int r = 0; r < 4; ++r)
          v[f][g][r] = (v[f][g][r] - mu[f][r]) * rs[f][r] * nw4[g] + nb4[g];
    // stats over x for the second LN
#pragma unroll
    for (int f = 0; f < 4; ++f)
#pragma unroll
      for (int r = 0; r < 4; ++r) {
        float s1 = 0.f, s2 = 0.f;
#pragma unroll
        for (int g = 0; g < 4; ++g) { s1 += v[f][g][r]; s2 += v[f][g][r] * v[f][g][r]; }
#pragma unroll
        for (int m = 1; m < 16; m <<= 1) { s1 += __shfl_xor(s1, m, 64); s2 += __shfl_xor(s2, m, 64); }
        if ((lane & 15) == 0) {
          int rowl = wr * 64 + f * 16 + (lane >> 4) * 4 + r;
          stB[(rowl * 4 + wc) * 2] = s1; stB[(rowl * 4 + wc) * 2 + 1] = s2;
        }
      }
    __syncthreads();
#pragma unroll
    for (int f = 0; f < 4; ++f)
#pragma unroll
      for (int r = 0; r < 4; ++r) {
        int rowl = wr * 64 + f * 16 + (lane >> 4) * 4 + r;
        float s1 = 0.f, s2 = 0.f;
#pragma unroll
        for (int q = 0; q < 4; ++q) { s1 += stB[(rowl * 4 + q) * 2]; s2 += stB[(rowl * 4 + q) * 2 + 1]; }
        float m2 = s1 * (1.f / 256.f);
        float r2 = rsqrtf(s2 * (1.f / 256.f) - m2 * m2 + 1e-5f);
        if ((lane & 15) == 0) { st2[rowl * 2] = m2; st2[rowl * 2 + 1] = r2; }
      }
    __syncthreads();
  }

  // transpose-store: per f, wave-private padded LDS tile, coalesced stores
  ushort* oh = (ushort*)out0;
#pragma unroll 1
  for (int f = 0; f < 4; ++f) {
#pragma unroll
    for (int g = 0; g < 4; ++g)
#pragma unroll
      for (int r = 0; r < 4; ++r)
        trw[((lane >> 4) * 4 + r) * 68 + (lane & 15) + g * 16] = v[f][g][r];
    const int lr2 = lane >> 2, cb2 = (lane & 3) * 16;
    float y[16];
#pragma unroll
    for (int i = 0; i < 4; ++i)
      *(float4*)&y[i * 4] = *(const float4*)&trw[lr2 * 68 + cb2 + i * 4];
    const size_t grow = row0 + wr * 64 + f * 16 + lr2;
    const int gc = col0 + wc * 64 + cb2;

    if (EPI == EPI_RES) {
      float mk = kmask[grow];
      float* of = (float*)out0;
#pragma unroll
      for (int i = 0; i < 4; ++i) {
        float4 xc = *(const float4*)&resid[grow * 256 + gc + i * 4];
        float4 o;
        o.x = (y[i * 4 + 0] + xc.x) * mk;
        o.y = (y[i * 4 + 1] + xc.y) * mk;
        o.z = (y[i * 4 + 2] + xc.z) * mk;
        o.w = (y[i * 4 + 3] + xc.w) * mk;
        *(float4*)&of[grow * ldo + gc + i * 4] = o;
      }
    } else {
      float z[16];
      if (EPI == EPI_SILU) {
#pragma unroll
        for (int i = 0; i < 16; ++i) z[i] = y[i] / (1.f + expf(-y[i]));
      } else if (EPI == EPI_GELU) {
#pragma unroll
        for (int i = 0; i < 16; ++i)
          z[i] = 0.5f * y[i] * (1.f + erff(y[i] * 0.70710678118654752f));
      } else if (EPI == EPI_LN) {
#pragma unroll
        for (int i = 0; i < 4; ++i) {
          float4 w4 = *(const float4*)&lnw[gc + i * 4];
          float4 a4 = *(const float4*)&lnb[gc + i * 4];
          z[i * 4 + 0] = y[i * 4 + 0] * w4.x + a4.x;
          z[i * 4 + 1] = y[i * 4 + 1] * w4.y + a4.y;
          z[i * 4 + 2] = y[i * 4 + 2] * w4.z + a4.z;
          z[i * 4 + 3] = y[i * 4 + 3] * w4.w + a4.w;
        }
      } else {  // EPI_LN2: y = x; write Xc, then second LN
        float m2 = st2[(wr * 64 + f * 16 + lr2) * 2];
        float r2 = st2[(wr * 64 + f * 16 + lr2) * 2 + 1];
#pragma unroll
        for (int i = 0; i < 4; ++i)
          *(float4*)&out_xc[grow * 256 + gc + i * 4] = *(const float4*)&y[i * 4];
#pragma unroll
        for (int i = 0; i < 4; ++i) {
          float4 w4 = *(const float4*)&ln2w[gc + i * 4];
          float4 a4 = *(const float4*)&ln2b[gc + i * 4];
          z[i * 4 + 0] = (y[i * 4 + 0] - m2) * r2 * w4.x + a4.x;
          z[i * 4 + 1] = (y[i * 4 + 1] - m2) * r2 * w4.y + a4.y;
          z[i * 4 + 2] = (y[i * 4 + 2] - m2) * r2 * w4.z + a4.z;
          z[i * 4 + 3] = (y[i * 4 + 3] - m2) * r2 * w4.w + a4.w;
        }
      }
      BF8 h0, l0, h1, l1;
#pragma unroll
      for (int e = 0; e < 8; ++e) {
        split_bf(z[e], h0.u[e], l0.u[e]);
        split_bf(z[8 + e], h1.u[e], l1.u[e]);
      }
      *(bf16x8*)&oh[grow * ldo + gc] = h0.v;
      *(bf16x8*)&oh[grow * ldo + gc + 8] = h1.v;
      *(bf16x8*)&out_lo[grow * ldo + gc] = l0.v;
      *(bf16x8*)&out_lo[grow * ldo + gc + 8] = l1.v;
    }
  }
}

// W[K][N] fp32 -> hi/lo [N][K] bf16
__global__ __launch_bounds__(256) void k_wprep(const float* __restrict__ W,
    ushort* __restrict__ Dh, ushort* __restrict__ Dl, int N, int kshift) {
  int idx = blockIdx.x * 256 + threadIdx.x;
  int K = 1 << kshift;
  int n = idx >> kshift, k = idx & (K - 1);
  float x = W[(size_t)k * N + n];
  ushort h, l;
  split_bf(x, h, l);
  Dh[idx] = h; Dl[idx] = l;
}

__global__ __launch_bounds__(256) void k_cat2(float* __restrict__ dst,
    const float* __restrict__ a, int na, const float* __restrict__ b, int nb) {
  int i = blockIdx.x * 256 + threadIdx.x;
  if (i < na) dst[i] = a[i];
  else if (i < na + nb) dst[i] = b[i - na];
}

extern "C" void kernel_launch(void* const* d_in, const int* in_sizes, int n_in,
                              void* d_out, int out_size, void* d_ws, size_t ws_size,
                              hipStream_t stream) {
  const float* slots  = (const float*)d_in[0];
  const float* keep   = (const float*)d_in[1];
  const float* fw_w1  = (const float*)d_in[2];
  const float* fw_b1  = (const float*)d_in[3];
  const float* fw_w2  = (const float*)d_in[4];
  const float* fw_b2  = (const float*)d_in[5];
  const float* fw_lnw = (const float*)d_in[6];
  const float* fw_lnb = (const float*)d_in[7];
  const float* bw_w1  = (const float*)d_in[8];
  const float* bw_b1  = (const float*)d_in[9];
  const float* bw_w2  = (const float*)d_in[10];
  const float* bw_b2  = (const float*)d_in[11];
  const float* bw_lnw = (const float*)d_in[12];
  const float* bw_lnb = (const float*)d_in[13];
  const float* mg_w   = (const float*)d_in[14];
  const float* mg_b   = (const float*)d_in[15];
  const float* nm_w   = (const float*)d_in[16];
  const float* nm_b   = (const float*)d_in[17];
  const float* ffn_lnw= (const float*)d_in[18];
  const float* ffn_lnb= (const float*)d_in[19];
  const float* ffn_w1 = (const float*)d_in[20];
  const float* ffn_b1 = (const float*)d_in[21];
  const float* ffn_w2 = (const float*)d_in[22];
  const float* ffn_b2 = (const float*)d_in[23];
  (void)n_in; (void)out_size;

  const int N = in_sizes[0] / 256;
  float* out = (float*)d_out;

  size_t off = 0;
  char* wsb = (char*)d_ws;
  auto alloc = [&](size_t bytes) -> void* {
    void* p = wsb + off;
    off = (off + bytes + 255) & ~(size_t)255;
    return p;
  };

  struct LayerW {
    ushort *l1h, *l1l, *l2h, *l2l, *mgh, *mgl, *f1h, *f1l, *f2h, *f2l;
    float *bl1, *bl2, *lncw, *lncb;
  } lw[2];
  for (int L = 0; L < 2; ++L) {
    lw[L].l1h = (ushort*)alloc(1024 * 256 * 2); lw[L].l1l = (ushort*)alloc(1024 * 256 * 2);
    lw[L].l2h = (ushort*)alloc(512 * 512 * 2);  lw[L].l2l = (ushort*)alloc(512 * 512 * 2);
    lw[L].mgh = (ushort*)alloc(256 * 512 * 2);  lw[L].mgl = (ushort*)alloc(256 * 512 * 2);
    lw[L].f1h = (ushort*)alloc(1024 * 256 * 2); lw[L].f1l = (ushort*)alloc(1024 * 256 * 2);
    lw[L].f2h = (ushort*)alloc(256 * 1024 * 2); lw[L].f2l = (ushort*)alloc(256 * 1024 * 2);
    lw[L].bl1 = (float*)alloc(1024 * 4);
    lw[L].bl2 = (float*)alloc(512 * 4);
    lw[L].lncw = (float*)alloc(512 * 4);
    lw[L].lncb = (float*)alloc(512 * 4);
  }

  size_t remain = ws_size > off + 4096 ? ws_size - off - 4096 : 0;
  int chunk = N;
  while ((size_t)chunk * 8192 > remain && chunk > 128) chunk >>= 1;

  ushort* H1h = (ushort*)alloc((size_t)chunk * 1024 * 2);
  ushort* H1l = (ushort*)alloc((size_t)chunk * 1024 * 2);
  ushort* Fh  = (ushort*)alloc((size_t)chunk * 512 * 2);
  ushort* Fl  = (ushort*)alloc((size_t)chunk * 512 * 2);
  float*  Xc  = (float*)alloc((size_t)chunk * 256 * 4);
  ushort* Hbh = (ushort*)alloc((size_t)chunk * 256 * 2);
  ushort* Hbl = (ushort*)alloc((size_t)chunk * 256 * 2);

  for (int L = 0; L < 2; ++L) {
    k_wprep<<<512, 256, 0, stream>>>(fw_w1 + (size_t)L * 256 * 512, lw[L].l1h, lw[L].l1l, 512, 8);
    k_wprep<<<512, 256, 0, stream>>>(bw_w1 + (size_t)L * 256 * 512, lw[L].l1h + 512 * 256, lw[L].l1l + 512 * 256, 512, 8);
    k_wprep<<<512, 256, 0, stream>>>(fw_w2 + (size_t)L * 512 * 256, lw[L].l2h, lw[L].l2l, 256, 9);
    k_wprep<<<512, 256, 0, stream>>>(bw_w2 + (size_t)L * 512 * 256, lw[L].l2h + 256 * 512, lw[L].l2l + 256 * 512, 256, 9);
    k_wprep<<<512, 256, 0, stream>>>(mg_w + (size_t)L * 512 * 256, lw[L].mgh, lw[L].mgl, 256, 9);
    k_wprep<<<1024, 256, 0, stream>>>(ffn_w1 + (size_t)L * 256 * 1024, lw[L].f1h, lw[L].f1l, 1024, 8);
    k_wprep<<<1024, 256, 0, stream>>>(ffn_w2 + (size_t)L * 1024 * 256, lw[L].f2h, lw[L].f2l, 256, 10);
    k_cat2<<<4, 256, 0, stream>>>(lw[L].bl1, fw_b1 + (size_t)L * 512, 512, bw_b1 + (size_t)L * 512, 512);
    k_cat2<<<2, 256, 0, stream>>>(lw[L].bl2, fw_b2 + (size_t)L * 256, 256, bw_b2 + (size_t)L * 256, 256);
    k_cat2<<<2, 256, 0, stream>>>(lw[L].lncw, fw_lnw + (size_t)L * 256, 256, bw_lnw + (size_t)L * 256, 256);
    k_cat2<<<2, 256, 0, stream>>>(lw[L].lncb, fw_lnb + (size_t)L * 256, 256, bw_lnb + (size_t)L * 256, 256);
  }

  dim3 blk(512);
  for (int L = 0; L < 2; ++L) {
    const float* Xsrc = (L == 0) ? slots : out;
    for (int c0 = 0; c0 < N; c0 += chunk) {
      const float* Xi = Xsrc + (size_t)c0 * 256;
      const int gx = chunk / 128;
      // 1. silu(X @ [fw_w1|bw_w1]) -> H1 hl [C][1024]
      k_gemm<8, EPI_SILU, true><<<dim3(gx, 4), blk, 0, stream>>>(
          Xi, nullptr, 256, 0, lw[L].l1h, lw[L].l1l, lw[L].bl1,
          nullptr, nullptr, nullptr, nullptr, nullptr, nullptr,
          H1h, H1l, 1024, nullptr);
      // 2. LN_branch(H1 @ W2 + b) -> F hl [C][512]
      k_gemm<16, EPI_LN, false><<<dim3(gx, 2), blk, 0, stream>>>(
          H1h, H1l, 1024, 512, lw[L].l2h, lw[L].l2l, lw[L].bl2,
          lw[L].lncw, lw[L].lncb, nullptr, nullptr, nullptr, nullptr,
          Fh, Fl, 512, nullptr);
      // 3. merge + residual + LN(nm) -> Xc, LN(ffn) -> Hb hl
      k_gemm<16, EPI_LN2, false><<<dim3(gx, 1), blk, 0, stream>>>(
          Fh, Fl, 512, 0, lw[L].mgh, lw[L].mgl, mg_b + (size_t)L * 256,
          nm_w + (size_t)L * 256, nm_b + (size_t)L * 256,
          ffn_lnw + (size_t)L * 256, ffn_lnb + (size_t)L * 256,
          Xi, nullptr, Hbh, Hbl, 256, Xc);
      // 4. gelu(Hb @ ffn_w1 + b) -> Ab hl (alias H1) [C][1024]
      k_gemm<8, EPI_GELU, false><<<dim3(gx, 4), blk, 0, stream>>>(
          Hbh, Hbl, 256, 0, lw[L].f1h, lw[L].f1l, ffn_b1 + (size_t)L * 1024,
          nullptr, nullptr, nullptr, nullptr, nullptr, nullptr,
          H1h, H1l, 1024, nullptr);
      // 5. (Xc + Ab @ ffn_w2 + b) * mask -> out fp32
      k_gemm<32, EPI_RES, false><<<dim3(gx, 1), blk, 0, stream>>>(
          H1h, H1l, 1024, 0, lw[L].f2h, lw[L].f2l, ffn_b2 + (size_t)L * 256,
          nullptr, nullptr, nullptr, nullptr, Xc, keep + c0,
          out + (size_t)c0 * 256, nullptr, 256, nullptr);
    }
  }
}

// Round 5
// 3962.948 us; speedup vs baseline: 2.1310x; 2.1310x over previous
//
#include <hip/hip_runtime.h>
#include <math.h>
#include <stdint.h>

typedef __attribute__((ext_vector_type(8))) short bf16x8;
typedef __attribute__((ext_vector_type(4))) float f32x4;

#define MFMA __builtin_amdgcn_mfma_f32_16x16x32_bf16

union BF8 { ushort u[8]; bf16x8 v; };

__device__ __forceinline__ void split_bf(float x, ushort& h, ushort& lo) {
  uint b = __float_as_uint(x);
  h = (ushort)(b >> 16);
  float hf = __uint_as_float((uint)h << 16);
  lo = (ushort)(__float_as_uint(x - hf) >> 16);
}
__device__ __forceinline__ float join_bf(ushort h, ushort l) {
  return __uint_as_float((uint)h << 16) + __uint_as_float((uint)l << 16);
}
__device__ __forceinline__ bf16x8 ld8(const ushort* p) { return *(const bf16x8*)p; }

// Fragment-linear layout: buffer[rt][kt][lane][8] ushorts, tile = 512 ushorts.
// A-frag: lane l holds row l&15, k = kt*32 + (l>>4)*8 + e.
// B-frag: lane l holds col l&15, k = kt*32 + (l>>4)*8 + e.
// C-frag [m89]: col = lane&15 (+g*16), row = (lane>>4)*4 + r (+f*16).

// ---------------------------------------------------------------------------
// KA: F = LN_branch(silu(X @ W1b + b1) @ W2b + b2).  64-token blocks, 4 waves.
// Slab-fused: 8 slabs of 64 H-cols; Hs handed off via LDS frags.
// ---------------------------------------------------------------------------
__global__ __launch_bounds__(256) void k_lin12(
    const ushort* __restrict__ Xh, const ushort* __restrict__ Xl,
    const ushort* __restrict__ fW1h, const ushort* __restrict__ fW1l,
    const ushort* __restrict__ bW1h, const ushort* __restrict__ bW1l,
    const ushort* __restrict__ fW2h, const ushort* __restrict__ fW2l,
    const ushort* __restrict__ bW2h, const ushort* __restrict__ bW2l,
    const float* __restrict__ fb1, const float* __restrict__ bb1,
    const float* __restrict__ fb2, const float* __restrict__ bb2,
    const float* __restrict__ flw, const float* __restrict__ flb,
    const float* __restrict__ blw, const float* __restrict__ blb,
    ushort* __restrict__ Fh, ushort* __restrict__ Fl) {
  __shared__ __align__(16) ushort HsH[4096], HsL[4096];
  __shared__ float trw[4][1088];
  __shared__ float st[512];
  const int tid = threadIdx.x, lane = tid & 63, w = tid >> 6;
  const int blk = blockIdx.x, br = blockIdx.y;
  const ushort* W1h = br ? bW1h : fW1h; const ushort* W1l = br ? bW1l : fW1l;
  const ushort* W2h = br ? bW2h : fW2h; const ushort* W2l = br ? bW2l : fW2l;
  const float* b1 = br ? bb1 : fb1;
  const float* b2 = br ? bb2 : fb2;
  const float* lw = br ? blw : flw;
  const float* lb = br ? blb : flb;

  f32x4 acc[4][4];
#pragma unroll
  for (int f = 0; f < 4; ++f)
#pragma unroll
    for (int g = 0; g < 4; ++g) acc[f][g] = (f32x4){0.f, 0.f, 0.f, 0.f};

  const size_t Ab = (size_t)blk * 4 * 8 * 512 + lane * 8;
  const int cIn = w * 16 + (lane & 15);
  const int kt2 = cIn >> 5, q = (cIn & 31) >> 3, e = cIn & 7;

#pragma unroll 1
  for (int s = 0; s < 8; ++s) {
    f32x4 a1[4];
#pragma unroll
    for (int f = 0; f < 4; ++f) a1[f] = (f32x4){0.f, 0.f, 0.f, 0.f};
    const size_t W1t = (size_t)(s * 4 + w) * 8 * 512 + lane * 8;
#pragma unroll 4
    for (int ks = 0; ks < 8; ++ks) {
      bf16x8 bh = ld8(&W1h[W1t + ks * 512]);
      bf16x8 bl = ld8(&W1l[W1t + ks * 512]);
#pragma unroll
      for (int f = 0; f < 4; ++f) {
        bf16x8 ah = ld8(&Xh[Ab + (f * 8 + ks) * 512]);
        bf16x8 al = ld8(&Xl[Ab + (f * 8 + ks) * 512]);
        a1[f] = MFMA(ah, bh, a1[f], 0, 0, 0);
        a1[f] = MFMA(al, bh, a1[f], 0, 0, 0);
        a1[f] = MFMA(ah, bl, a1[f], 0, 0, 0);
      }
    }
    const float bias1 = b1[s * 64 + cIn];
    __syncthreads();  // prior slab's GEMM2 LDS reads done
#pragma unroll
    for (int f = 0; f < 4; ++f)
#pragma unroll
      for (int r = 0; r < 4; ++r) {
        float x = a1[f][r] + bias1;
        x = x / (1.f + expf(-x));
        ushort hh, ll; split_bf(x, hh, ll);
        int R15 = (lane >> 4) * 4 + r;
        int idx = (f * 2 + kt2) * 512 + (q * 16 + R15) * 8 + e;
        HsH[idx] = hh; HsL[idx] = ll;
      }
    __syncthreads();
#pragma unroll
    for (int ks = 0; ks < 2; ++ks) {
      bf16x8 ah[4], al[4], bh[4], bl[4];
#pragma unroll
      for (int f = 0; f < 4; ++f) {
        ah[f] = ld8(&HsH[(f * 2 + ks) * 512 + lane * 8]);
        al[f] = ld8(&HsL[(f * 2 + ks) * 512 + lane * 8]);
      }
#pragma unroll
      for (int g = 0; g < 4; ++g) {
        size_t bt = ((size_t)(w * 4 + g) * 16 + (s * 2 + ks)) * 512 + lane * 8;
        bh[g] = ld8(&W2h[bt]);
        bl[g] = ld8(&W2l[bt]);
      }
#pragma unroll
      for (int f = 0; f < 4; ++f)
#pragma unroll
        for (int g = 0; g < 4; ++g) {
          acc[f][g] = MFMA(ah[f], bh[g], acc[f][g], 0, 0, 0);
          acc[f][g] = MFMA(al[f], bh[g], acc[f][g], 0, 0, 0);
          acc[f][g] = MFMA(ah[f], bl[g], acc[f][g], 0, 0, 0);
        }
    }
  }

  // epilogue: bias + branch LN -> F frag  (transpose via per-wave padded LDS)
  float y[4][16];
  const int lr = lane >> 2, cq = (lane & 3) * 16;
  const int colL = w * 64 + cq;
#pragma unroll
  for (int f = 0; f < 4; ++f) {
#pragma unroll
    for (int g = 0; g < 4; ++g)
#pragma unroll
      for (int r = 0; r < 4; ++r)
        trw[w][((lane >> 4) * 4 + r) * 68 + g * 16 + (lane & 15)] = acc[f][g][r];
    float s1 = 0.f, s2 = 0.f;
#pragma unroll
    for (int i = 0; i < 4; ++i) {
      float4 t = *(const float4*)&trw[w][lr * 68 + cq + i * 4];
      float4 bb = *(const float4*)&b2[colL + i * 4];
      y[f][i * 4 + 0] = t.x + bb.x; y[f][i * 4 + 1] = t.y + bb.y;
      y[f][i * 4 + 2] = t.z + bb.z; y[f][i * 4 + 3] = t.w + bb.w;
#pragma unroll
      for (int q2 = 0; q2 < 4; ++q2) {
        float v = y[f][i * 4 + q2]; s1 += v; s2 += v * v;
      }
    }
    s1 += __shfl_xor(s1, 1, 64); s2 += __shfl_xor(s2, 1, 64);
    s1 += __shfl_xor(s1, 2, 64); s2 += __shfl_xor(s2, 2, 64);
    if ((lane & 3) == 0) {
      int row = f * 16 + lr;
      st[row * 8 + w * 2] = s1; st[row * 8 + w * 2 + 1] = s2;
    }
  }
  __syncthreads();
#pragma unroll
  for (int f = 0; f < 4; ++f) {
    int row = f * 16 + lr;
    float s1 = 0.f, s2 = 0.f;
#pragma unroll
    for (int q2 = 0; q2 < 4; ++q2) { s1 += st[row * 8 + q2 * 2]; s2 += st[row * 8 + q2 * 2 + 1]; }
    float mu = s1 * (1.f / 256.f);
    float rs = rsqrtf(s2 * (1.f / 256.f) - mu * mu + 1e-5f);
    BF8 h0, l0, h1, l1;
#pragma unroll
    for (int i = 0; i < 16; ++i) {
      float z = (y[f][i] - mu) * rs * lw[colL + i] + lb[colL + i];
      ushort hh, ll; split_bf(z, hh, ll);
      if (i < 8) { h0.u[i] = hh; l0.u[i] = ll; } else { h1.u[i - 8] = hh; l1.u[i - 8] = ll; }
    }
    int R = blk * 64 + row;
    int Cg = br * 256 + colL;
    size_t base = ((size_t)(R >> 4) * 16 + (Cg >> 5)) * 512;
    int q0 = (Cg & 31) >> 3;
    *(bf16x8*)&Fh[base + (q0 * 16 + lr) * 8] = h0.v;
    *(bf16x8*)&Fh[base + ((q0 + 1) * 16 + lr) * 8] = h1.v;
    *(bf16x8*)&Fl[base + (q0 * 16 + lr) * 8] = l0.v;
    *(bf16x8*)&Fl[base + ((q0 + 1) * 16 + lr) * 8] = l1.v;
  }
}

// ---------------------------------------------------------------------------
// KB: M = F @ mg + b; Xc = LN(resid + M, nm); Hb = LN(Xc, ffn_ln).
// ---------------------------------------------------------------------------
__global__ __launch_bounds__(256) void k_mergep(
    const ushort* __restrict__ Fh, const ushort* __restrict__ Fl,
    const ushort* __restrict__ Mh, const ushort* __restrict__ Ml,
    const float* __restrict__ mgb,
    const ushort* __restrict__ Rh, const ushort* __restrict__ Rl,
    const float* __restrict__ nmw, const float* __restrict__ nmb,
    const float* __restrict__ fw, const float* __restrict__ fb,
    ushort* __restrict__ Xch, ushort* __restrict__ Xcl,
    ushort* __restrict__ Hbh, ushort* __restrict__ Hbl) {
  __shared__ float trw[4][1088];
  __shared__ float st[512], stB[512];
  const int tid = threadIdx.x, lane = tid & 63, w = tid >> 6;
  const int blk = blockIdx.x;

  f32x4 acc[4][4];
#pragma unroll
  for (int f = 0; f < 4; ++f)
#pragma unroll
    for (int g = 0; g < 4; ++g) acc[f][g] = (f32x4){0.f, 0.f, 0.f, 0.f};

  const size_t Ab = (size_t)blk * 4 * 16 * 512 + lane * 8;
#pragma unroll 2
  for (int ks = 0; ks < 16; ++ks) {
    bf16x8 bh[4], bl[4];
#pragma unroll
    for (int g = 0; g < 4; ++g) {
      size_t bt = ((size_t)(w * 4 + g) * 16 + ks) * 512 + lane * 8;
      bh[g] = ld8(&Mh[bt]); bl[g] = ld8(&Ml[bt]);
    }
#pragma unroll
    for (int f = 0; f < 4; ++f) {
      bf16x8 ah = ld8(&Fh[Ab + (f * 16 + ks) * 512]);
      bf16x8 al = ld8(&Fl[Ab + (f * 16 + ks) * 512]);
#pragma unroll
      for (int g = 0; g < 4; ++g) {
        acc[f][g] = MFMA(ah, bh[g], acc[f][g], 0, 0, 0);
        acc[f][g] = MFMA(al, bh[g], acc[f][g], 0, 0, 0);
        acc[f][g] = MFMA(ah, bl[g], acc[f][g], 0, 0, 0);
      }
    }
  }

  float y[4][16];
  const int lr = lane >> 2, cq = (lane & 3) * 16;
  const int colL = w * 64 + cq;
  // phase 1: transpose + bias + residual; stats1
#pragma unroll
  for (int f = 0; f < 4; ++f) {
#pragma unroll
    for (int g = 0; g < 4; ++g)
#pragma unroll
      for (int r = 0; r < 4; ++r)
        trw[w][((lane >> 4) * 4 + r) * 68 + g * 16 + (lane & 15)] = acc[f][g][r];
    int R = blk * 64 + f * 16 + lr;
    size_t base = ((size_t)(R >> 4) * 8 + (colL >> 5)) * 512;
    int q0 = (colL & 31) >> 3;
    bf16x8 rh0 = ld8(&Rh[base + (q0 * 16 + lr) * 8]);
    bf16x8 rh1 = ld8(&Rh[base + ((q0 + 1) * 16 + lr) * 8]);
    bf16x8 rl0 = ld8(&Rl[base + (q0 * 16 + lr) * 8]);
    bf16x8 rl1 = ld8(&Rl[base + ((q0 + 1) * 16 + lr) * 8]);
    float s1 = 0.f, s2 = 0.f;
#pragma unroll
    for (int i = 0; i < 4; ++i) {
      float4 t = *(const float4*)&trw[w][lr * 68 + cq + i * 4];
      float4 bb = *(const float4*)&mgb[colL + i * 4];
      float tv[4] = {t.x + bb.x, t.y + bb.y, t.z + bb.z, t.w + bb.w};
#pragma unroll
      for (int q2 = 0; q2 < 4; ++q2) {
        int ii = i * 4 + q2;
        float rv = (ii < 8) ? join_bf((ushort)rh0[ii], (ushort)rl0[ii])
                            : join_bf((ushort)rh1[ii - 8], (ushort)rl1[ii - 8]);
        float v = tv[q2] + rv;
        y[f][ii] = v; s1 += v; s2 += v * v;
      }
    }
    s1 += __shfl_xor(s1, 1, 64); s2 += __shfl_xor(s2, 1, 64);
    s1 += __shfl_xor(s1, 2, 64); s2 += __shfl_xor(s2, 2, 64);
    if ((lane & 3) == 0) {
      int row = f * 16 + lr;
      st[row * 8 + w * 2] = s1; st[row * 8 + w * 2 + 1] = s2;
    }
  }
  __syncthreads();
  // phase 2: LN1 -> Xc; stats2
#pragma unroll
  for (int f = 0; f < 4; ++f) {
    int row = f * 16 + lr;
    float s1 = 0.f, s2 = 0.f;
#pragma unroll
    for (int q2 = 0; q2 < 4; ++q2) { s1 += st[row * 8 + q2 * 2]; s2 += st[row * 8 + q2 * 2 + 1]; }
    float mu = s1 * (1.f / 256.f);
    float rs = rsqrtf(s2 * (1.f / 256.f) - mu * mu + 1e-5f);
    BF8 h0, l0, h1, l1;
    float t1 = 0.f, t2 = 0.f;
#pragma unroll
    for (int i = 0; i < 16; ++i) {
      float x = (y[f][i] - mu) * rs * nmw[colL + i] + nmb[colL + i];
      y[f][i] = x; t1 += x; t2 += x * x;
      ushort hh, ll; split_bf(x, hh, ll);
      if (i < 8) { h0.u[i] = hh; l0.u[i] = ll; } else { h1.u[i - 8] = hh; l1.u[i - 8] = ll; }
    }
    int R = blk * 64 + row;
    size_t base = ((size_t)(R >> 4) * 8 + (colL >> 5)) * 512;
    int q0 = (colL & 31) >> 3;
    *(bf16x8*)&Xch[base + (q0 * 16 + lr) * 8] = h0.v;
    *(bf16x8*)&Xch[base + ((q0 + 1) * 16 + lr) * 8] = h1.v;
    *(bf16x8*)&Xcl[base + (q0 * 16 + lr) * 8] = l0.v;
    *(bf16x8*)&Xcl[base + ((q0 + 1) * 16 + lr) * 8] = l1.v;
    t1 += __shfl_xor(t1, 1, 64); t2 += __shfl_xor(t2, 1, 64);
    t1 += __shfl_xor(t1, 2, 64); t2 += __shfl_xor(t2, 2, 64);
    if ((lane & 3) == 0) { stB[row * 8 + w * 2] = t1; stB[row * 8 + w * 2 + 1] = t2; }
  }
  __syncthreads();
  // phase 3: LN2 -> Hb
#pragma unroll
  for (int f = 0; f < 4; ++f) {
    int row = f * 16 + lr;
    float s1 = 0.f, s2 = 0.f;
#pragma unroll
    for (int q2 = 0; q2 < 4; ++q2) { s1 += stB[row * 8 + q2 * 2]; s2 += stB[row * 8 + q2 * 2 + 1]; }
    float mu = s1 * (1.f / 256.f);
    float rs = rsqrtf(s2 * (1.f / 256.f) - mu * mu + 1e-5f);
    BF8 h0, l0, h1, l1;
#pragma unroll
    for (int i = 0; i < 16; ++i) {
      float z = (y[f][i] - mu) * rs * fw[colL + i] + fb[colL + i];
      ushort hh, ll; split_bf(z, hh, ll);
      if (i < 8) { h0.u[i] = hh; l0.u[i] = ll; } else { h1.u[i - 8] = hh; l1.u[i - 8] = ll; }
    }
    int R = blk * 64 + row;
    size_t base = ((size_t)(R >> 4) * 8 + (colL >> 5)) * 512;
    int q0 = (colL & 31) >> 3;
    *(bf16x8*)&Hbh[base + (q0 * 16 + lr) * 8] = h0.v;
    *(bf16x8*)&Hbh[base + ((q0 + 1) * 16 + lr) * 8] = h1.v;
    *(bf16x8*)&Hbl[base + (q0 * 16 + lr) * 8] = l0.v;
    *(bf16x8*)&Hbl[base + ((q0 + 1) * 16 + lr) * 8] = l1.v;
  }
}

// ---------------------------------------------------------------------------
// KC: out = (Xc + gelu(Hb @ W1 + b1) @ W2 + b2) * mask.  16 slabs of 64.
// ---------------------------------------------------------------------------
template<bool FINAL>
__global__ __launch_bounds__(256) void k_ffn(
    const ushort* __restrict__ Hbh, const ushort* __restrict__ Hbl,
    const ushort* __restrict__ W1h, const ushort* __restrict__ W1l,
    const float* __restrict__ b1,
    const ushort* __restrict__ W2h, const ushort* __restrict__ W2l,
    const float* __restrict__ b2,
    const ushort* __restrict__ Xch, const ushort* __restrict__ Xcl,
    const float* __restrict__ keep,
    float* __restrict__ outf, ushort* __restrict__ Oh, ushort* __restrict__ Ol) {
  __shared__ __align__(16) ushort HsH[4096], HsL[4096];
  __shared__ float trw[4][1088];
  const int tid = threadIdx.x, lane = tid & 63, w = tid >> 6;
  const int blk = blockIdx.x;

  f32x4 acc[4][4];
#pragma unroll
  for (int f = 0; f < 4; ++f)
#pragma unroll
    for (int g = 0; g < 4; ++g) acc[f][g] = (f32x4){0.f, 0.f, 0.f, 0.f};

  const size_t Ab = (size_t)blk * 4 * 8 * 512 + lane * 8;
  const int cIn = w * 16 + (lane & 15);
  const int kt2 = cIn >> 5, q = (cIn & 31) >> 3, e = cIn & 7;

#pragma unroll 1
  for (int s = 0; s < 16; ++s) {
    f32x4 a1[4];
#pragma unroll
    for (int f = 0; f < 4; ++f) a1[f] = (f32x4){0.f, 0.f, 0.f, 0.f};
    const size_t W1t = (size_t)(s * 4 + w) * 8 * 512 + lane * 8;
#pragma unroll 4
    for (int ks = 0; ks < 8; ++ks) {
      bf16x8 bh = ld8(&W1h[W1t + ks * 512]);
      bf16x8 bl = ld8(&W1l[W1t + ks * 512]);
#pragma unroll
      for (int f = 0; f < 4; ++f) {
        bf16x8 ah = ld8(&Hbh[Ab + (f * 8 + ks) * 512]);
        bf16x8 al = ld8(&Hbl[Ab + (f * 8 + ks) * 512]);
        a1[f] = MFMA(ah, bh, a1[f], 0, 0, 0);
        a1[f] = MFMA(al, bh, a1[f], 0, 0, 0);
        a1[f] = MFMA(ah, bl, a1[f], 0, 0, 0);
      }
    }
    const float bias1 = b1[s * 64 + cIn];
    __syncthreads();
#pragma unroll
    for (int f = 0; f < 4; ++f)
#pragma unroll
      for (int r = 0; r < 4; ++r) {
        float x = a1[f][r] + bias1;
        x = 0.5f * x * (1.f + erff(x * 0.70710678118654752f));
        ushort hh, ll; split_bf(x, hh, ll);
        int R15 = (lane >> 4) * 4 + r;
        int idx = (f * 2 + kt2) * 512 + (q * 16 + R15) * 8 + e;
        HsH[idx] = hh; HsL[idx] = ll;
      }
    __syncthreads();
#pragma unroll
    for (int ks = 0; ks < 2; ++ks) {
      bf16x8 ah[4], al[4], bh[4], bl[4];
#pragma unroll
      for (int f = 0; f < 4; ++f) {
        ah[f] = ld8(&HsH[(f * 2 + ks) * 512 + lane * 8]);
        al[f] = ld8(&HsL[(f * 2 + ks) * 512 + lane * 8]);
      }
#pragma unroll
      for (int g = 0; g < 4; ++g) {
        size_t bt = ((size_t)(w * 4 + g) * 32 + (s * 2 + ks)) * 512 + lane * 8;
        bh[g] = ld8(&W2h[bt]);
        bl[g] = ld8(&W2l[bt]);
      }
#pragma unroll
      for (int f = 0; f < 4; ++f)
#pragma unroll
        for (int g = 0; g < 4; ++g) {
          acc[f][g] = MFMA(ah[f], bh[g], acc[f][g], 0, 0, 0);
          acc[f][g] = MFMA(al[f], bh[g], acc[f][g], 0, 0, 0);
          acc[f][g] = MFMA(ah[f], bl[g], acc[f][g], 0, 0, 0);
        }
    }
  }

  // epilogue: + b2 + Xc, * mask -> fp32 out (FINAL) or frag (layer 0)
  const int lr = lane >> 2, cq = (lane & 3) * 16;
  const int colL = w * 64 + cq;
#pragma unroll
  for (int f = 0; f < 4; ++f) {
#pragma unroll
    for (int g = 0; g < 4; ++g)
#pragma unroll
      for (int r = 0; r < 4; ++r)
        trw[w][((lane >> 4) * 4 + r) * 68 + g * 16 + (lane & 15)] = acc[f][g][r];
    int row = f * 16 + lr;
    int R = blk * 64 + row;
    float mk = keep[R];
    size_t base = ((size_t)(R >> 4) * 8 + (colL >> 5)) * 512;
    int q0 = (colL & 31) >> 3;
    bf16x8 rh0 = ld8(&Xch[base + (q0 * 16 + lr) * 8]);
    bf16x8 rh1 = ld8(&Xch[base + ((q0 + 1) * 16 + lr) * 8]);
    bf16x8 rl0 = ld8(&Xcl[base + (q0 * 16 + lr) * 8]);
    bf16x8 rl1 = ld8(&Xcl[base + ((q0 + 1) * 16 + lr) * 8]);
    float z[16];
#pragma unroll
    for (int i = 0; i < 4; ++i) {
      float4 t = *(const float4*)&trw[w][lr * 68 + cq + i * 4];
      float4 bb = *(const float4*)&b2[colL + i * 4];
      float tv[4] = {t.x + bb.x, t.y + bb.y, t.z + bb.z, t.w + bb.w};
#pragma unroll
      for (int q2 = 0; q2 < 4; ++q2) {
        int ii = i * 4 + q2;
        float rv = (ii < 8) ? join_bf((ushort)rh0[ii], (ushort)rl0[ii])
                            : join_bf((ushort)rh1[ii - 8], (ushort)rl1[ii - 8]);
        z[ii] = (rv + tv[q2]) * mk;
      }
    }
    if (FINAL) {
#pragma unroll
      for (int i = 0; i < 4; ++i)
        *(float4*)&outf[(size_t)R * 256 + colL + i * 4] = *(const float4*)&z[i * 4];
    } else {
      BF8 h0, l0, h1, l1;
#pragma unroll
      for (int i = 0; i < 16; ++i) {
        ushort hh, ll; split_bf(z[i], hh, ll);
        if (i < 8) { h0.u[i] = hh; l0.u[i] = ll; } else { h1.u[i - 8] = hh; l1.u[i - 8] = ll; }
      }
      *(bf16x8*)&Oh[base + (q0 * 16 + lr) * 8] = h0.v;
      *(bf16x8*)&Oh[base + ((q0 + 1) * 16 + lr) * 8] = h1.v;
      *(bf16x8*)&Ol[base + (q0 * 16 + lr) * 8] = l0.v;
      *(bf16x8*)&Ol[base + ((q0 + 1) * 16 + lr) * 8] = l1.v;
    }
  }
}

// X fp32 row-major [rows][256] -> A-frag hl (nkt=8)
__global__ __launch_bounds__(256) void k_xprep(const float* __restrict__ X,
    ushort* __restrict__ Dh, ushort* __restrict__ Dl) {
  int t = blockIdx.x * 4 + (threadIdx.x >> 6);
  int lane = threadIdx.x & 63;
  int rt = t >> 3, kt = t & 7;
  const float* sp = X + (size_t)(rt * 16 + (lane & 15)) * 256 + kt * 32 + (lane >> 4) * 8;
  float4 a = *(const float4*)sp;
  float4 b = *(const float4*)(sp + 4);
  float xs[8] = {a.x, a.y, a.z, a.w, b.x, b.y, b.z, b.w};
  BF8 h, l;
#pragma unroll
  for (int e = 0; e < 8; ++e) split_bf(xs[e], h.u[e], l.u[e]);
  *(bf16x8*)&Dh[(size_t)t * 512 + lane * 8] = h.v;
  *(bf16x8*)&Dl[(size_t)t * 512 + lane * 8] = l.v;
}

// W fp32 [K][Nout] -> B-frag hl [Nout/16][K/32]
__global__ __launch_bounds__(256) void k_wprep(const float* __restrict__ W,
    ushort* __restrict__ Dh, ushort* __restrict__ Dl, int Nout, int K) {
  int t = blockIdx.x * 4 + (threadIdx.x >> 6);
  int lane = threadIdx.x & 63;
  int nkt = K >> 5;
  int nt = t / nkt, kt = t % nkt;
  int n = nt * 16 + (lane & 15);
  int k0 = kt * 32 + (lane >> 4) * 8;
  BF8 h, l;
#pragma unroll
  for (int e = 0; e < 8; ++e) {
    float x = W[(size_t)(k0 + e) * Nout + n];
    split_bf(x, h.u[e], l.u[e]);
  }
  *(bf16x8*)&Dh[(size_t)t * 512 + lane * 8] = h.v;
  *(bf16x8*)&Dl[(size_t)t * 512 + lane * 8] = l.v;
}

extern "C" void kernel_launch(void* const* d_in, const int* in_sizes, int n_in,
                              void* d_out, int out_size, void* d_ws, size_t ws_size,
                              hipStream_t stream) {
  const float* slots  = (const float*)d_in[0];
  const float* keep   = (const float*)d_in[1];
  const float* fw_w1  = (const float*)d_in[2];
  const float* fw_b1  = (const float*)d_in[3];
  const float* fw_w2  = (const float*)d_in[4];
  const float* fw_b2  = (const float*)d_in[5];
  const float* fw_lnw = (const float*)d_in[6];
  const float* fw_lnb = (const float*)d_in[7];
  const float* bw_w1  = (const float*)d_in[8];
  const float* bw_b1  = (const float*)d_in[9];
  const float* bw_w2  = (const float*)d_in[10];
  const float* bw_b2  = (const float*)d_in[11];
  const float* bw_lnw = (const float*)d_in[12];
  const float* bw_lnb = (const float*)d_in[13];
  const float* mg_w   = (const float*)d_in[14];
  const float* mg_b   = (const float*)d_in[15];
  const float* nm_w   = (const float*)d_in[16];
  const float* nm_b   = (const float*)d_in[17];
  const float* ffn_lnw= (const float*)d_in[18];
  const float* ffn_lnb= (const float*)d_in[19];
  const float* ffn_w1 = (const float*)d_in[20];
  const float* ffn_b1 = (const float*)d_in[21];
  const float* ffn_w2 = (const float*)d_in[22];
  const float* ffn_b2 = (const float*)d_in[23];
  (void)n_in; (void)out_size;

  const int N = in_sizes[0] / 256;
  float* out = (float*)d_out;

  size_t off = 0;
  char* wsb = (char*)d_ws;
  auto allocU = [&](size_t elems) -> ushort* {
    void* p = wsb + off;
    off = (off + elems * 2 + 255) & ~(size_t)255;
    return (ushort*)p;
  };

  struct LayerW {
    ushort *fw1h, *fw1l, *bw1h, *bw1l, *fw2h, *fw2l, *bw2h, *bw2l;
    ushort *mgh, *mgl, *f1h, *f1l, *f2h, *f2l;
  } lw[2];
  for (int L = 0; L < 2; ++L) {
    lw[L].fw1h = allocU(131072); lw[L].fw1l = allocU(131072);
    lw[L].bw1h = allocU(131072); lw[L].bw1l = allocU(131072);
    lw[L].fw2h = allocU(131072); lw[L].fw2l = allocU(131072);
    lw[L].bw2h = allocU(131072); lw[L].bw2l = allocU(131072);
    lw[L].mgh  = allocU(131072); lw[L].mgl  = allocU(131072);
    lw[L].f1h  = allocU(262144); lw[L].f1l  = allocU(262144);
    lw[L].f2h  = allocU(262144); lw[L].f2l  = allocU(262144);
  }

  size_t remain = ws_size > off + 4096 ? ws_size - off - 4096 : 0;
  int chunk = N;
  while ((size_t)chunk * 6144 > remain && chunk > 512) chunk >>= 1;

  ushort* Xfh = allocU((size_t)chunk * 256); ushort* Xfl = allocU((size_t)chunk * 256);
  ushort* Fh  = allocU((size_t)chunk * 512); ushort* Fl  = allocU((size_t)chunk * 512);
  ushort* Xch = allocU((size_t)chunk * 256); ushort* Xcl = allocU((size_t)chunk * 256);
  ushort* Hbh = allocU((size_t)chunk * 256); ushort* Hbl = allocU((size_t)chunk * 256);
  ushort* X2h = allocU((size_t)chunk * 256); ushort* X2l = allocU((size_t)chunk * 256);

  // weight prep (once)
  for (int L = 0; L < 2; ++L) {
    k_wprep<<<64, 256, 0, stream>>>(fw_w1 + (size_t)L * 131072, lw[L].fw1h, lw[L].fw1l, 512, 256);
    k_wprep<<<64, 256, 0, stream>>>(bw_w1 + (size_t)L * 131072, lw[L].bw1h, lw[L].bw1l, 512, 256);
    k_wprep<<<64, 256, 0, stream>>>(fw_w2 + (size_t)L * 131072, lw[L].fw2h, lw[L].fw2l, 256, 512);
    k_wprep<<<64, 256, 0, stream>>>(bw_w2 + (size_t)L * 131072, lw[L].bw2h, lw[L].bw2l, 256, 512);
    k_wprep<<<64, 256, 0, stream>>>(mg_w + (size_t)L * 131072, lw[L].mgh, lw[L].mgl, 256, 512);
    k_wprep<<<128, 256, 0, stream>>>(ffn_w1 + (size_t)L * 262144, lw[L].f1h, lw[L].f1l, 1024, 256);
    k_wprep<<<128, 256, 0, stream>>>(ffn_w2 + (size_t)L * 262144, lw[L].f2h, lw[L].f2l, 256, 1024);
  }

  for (int c0 = 0; c0 < N; c0 += chunk) {
    k_xprep<<<(chunk / 16) * 2, 256, 0, stream>>>(slots + (size_t)c0 * 256, Xfh, Xfl);
    const int gx = chunk / 64;
    for (int L = 0; L < 2; ++L) {
      const ushort* Xh = (L == 0) ? Xfh : X2h;
      const ushort* Xl = (L == 0) ? Xfl : X2l;
      k_lin12<<<dim3(gx, 2), 256, 0, stream>>>(
          Xh, Xl,
          lw[L].fw1h, lw[L].fw1l, lw[L].bw1h, lw[L].bw1l,
          lw[L].fw2h, lw[L].fw2l, lw[L].bw2h, lw[L].bw2l,
          fw_b1 + (size_t)L * 512, bw_b1 + (size_t)L * 512,
          fw_b2 + (size_t)L * 256, bw_b2 + (size_t)L * 256,
          fw_lnw + (size_t)L * 256, fw_lnb + (size_t)L * 256,
          bw_lnw + (size_t)L * 256, bw_lnb + (size_t)L * 256,
          Fh, Fl);
      k_mergep<<<gx, 256, 0, stream>>>(
          Fh, Fl, lw[L].mgh, lw[L].mgl, mg_b + (size_t)L * 256,
          Xh, Xl,
          nm_w + (size_t)L * 256, nm_b + (size_t)L * 256,
          ffn_lnw + (size_t)L * 256, ffn_lnb + (size_t)L * 256,
          Xch, Xcl, Hbh, Hbl);
      if (L == 0) {
        k_ffn<false><<<gx, 256, 0, stream>>>(
            Hbh, Hbl, lw[L].f1h, lw[L].f1l, ffn_b1 + (size_t)L * 1024,
            lw[L].f2h, lw[L].f2l, ffn_b2 + (size_t)L * 256,
            Xch, Xcl, keep + c0, nullptr, X2h, X2l);
      } else {
        k_ffn<true><<<gx, 256, 0, stream>>>(
            Hbh, Hbl, lw[L].f1h, lw[L].f1l, ffn_b1 + (size_t)L * 1024,
            lw[L].f2h, lw[L].f2l, ffn_b2 + (size_t)L * 256,
            Xch, Xcl, keep + c0, out + (size_t)c0 * 256, nullptr, nullptr);
      }
    }
  }
}

// Round 6
// 3029.554 us; speedup vs baseline: 2.7875x; 1.3081x over previous
//
#include <hip/hip_runtime.h>
#include <math.h>
#include <stdint.h>

typedef __attribute__((ext_vector_type(8))) short bf16x8;
typedef __attribute__((ext_vector_type(4))) float f32x4;

#define MFMA __builtin_amdgcn_mfma_f32_16x16x32_bf16

union BF8 { ushort u[8]; bf16x8 v; };

__device__ __forceinline__ void split_bf(float x, ushort& h, ushort& lo) {
  uint b = __float_as_uint(x);
  h = (ushort)(b >> 16);
  float hf = __uint_as_float((uint)h << 16);
  lo = (ushort)(__float_as_uint(x - hf) >> 16);
}
__device__ __forceinline__ float join_bf(ushort h, ushort l) {
  return __uint_as_float((uint)h << 16) + __uint_as_float((uint)l << 16);
}
__device__ __forceinline__ bf16x8 ld8(const ushort* p) { return *(const bf16x8*)p; }

// Fragment-linear layout: buffer[rt][kt][lane][8] ushorts, tile = 512 ushorts.
// A-frag: lane l holds row l&15, k = kt*32 + (l>>4)*8 + e.
// B-frag: lane l holds col l&15, k = kt*32 + (l>>4)*8 + e.
// C-frag [m89]: col = lane&15 (+g*16), row = (lane>>4)*4 + r (+f*16).
//
// Block = 64 tokens, 512 threads, 8 waves: h = w>>2 (token half, 32 rows),
// c = w&3 (col quarter, 64 of 256 out cols). acc[2][4] = 32 VGPRs/wave.

// ---------------------------------------------------------------------------
// KA: F = LN_branch(silu(X @ W1b + b1) @ W2b + b2), 8 slabs of 64 H-cols,
// Hs double-buffered in LDS, 1 barrier per slab.
// ---------------------------------------------------------------------------
__global__ __launch_bounds__(512) void k_lin12(
    const ushort* __restrict__ Xh, const ushort* __restrict__ Xl,
    const ushort* __restrict__ fW1h, const ushort* __restrict__ fW1l,
    const ushort* __restrict__ bW1h, const ushort* __restrict__ bW1l,
    const ushort* __restrict__ fW2h, const ushort* __restrict__ fW2l,
    const ushort* __restrict__ bW2h, const ushort* __restrict__ bW2l,
    const float* __restrict__ fb1, const float* __restrict__ bb1,
    const float* __restrict__ fb2, const float* __restrict__ bb2,
    const float* __restrict__ flw, const float* __restrict__ flb,
    const float* __restrict__ blw, const float* __restrict__ blb,
    ushort* __restrict__ Fh, ushort* __restrict__ Fl) {
  __shared__ __align__(16) char lraw[36864];  // Hs dbuf (32KB) / trw (34.8KB)
  __shared__ float st[512];
  ushort* HsH = (ushort*)lraw;             // [2][4096]
  ushort* HsL = (ushort*)(lraw + 16384);   // [2][4096]
  float* trw = (float*)lraw;               // [8][1088] epilogue only

  const int tid = threadIdx.x, lane = tid & 63, w = tid >> 6;
  const int h = w >> 2, c = w & 3;
  const int blk = blockIdx.x, br = blockIdx.y;
  const ushort* W1h = br ? bW1h : fW1h; const ushort* W1l = br ? bW1l : fW1l;
  const ushort* W2h = br ? bW2h : fW2h; const ushort* W2l = br ? bW2l : fW2l;
  const float* b1 = br ? bb1 : fb1;
  const float* b2 = br ? bb2 : fb2;
  const float* lw = br ? blw : flw;
  const float* lb = br ? blb : flb;

  f32x4 acc[2][4];
#pragma unroll
  for (int f = 0; f < 2; ++f)
#pragma unroll
    for (int g = 0; g < 4; ++g) acc[f][g] = (f32x4){0.f, 0.f, 0.f, 0.f};

  auto gemm1 = [&](int s, f32x4* a1) {
#pragma unroll 4
    for (int kt = 0; kt < 8; ++kt) {
      size_t wt = ((size_t)(s * 4 + c) * 8 + kt) * 512 + lane * 8;
      bf16x8 bh = ld8(&W1h[wt]), bl = ld8(&W1l[wt]);
#pragma unroll
      for (int f = 0; f < 2; ++f) {
        size_t at = ((size_t)(blk * 4 + h * 2 + f) * 8 + kt) * 512 + lane * 8;
        bf16x8 ah = ld8(&Xh[at]), al = ld8(&Xl[at]);
        a1[f] = MFMA(ah, bh, a1[f], 0, 0, 0);
        a1[f] = MFMA(al, bh, a1[f], 0, 0, 0);
        a1[f] = MFMA(ah, bl, a1[f], 0, 0, 0);
      }
    }
  };
  auto hswr = [&](int s, f32x4* a1) {
    const int buf = (s & 1) * 4096;
    const float bias1 = b1[s * 64 + c * 16 + (lane & 15)];
    const int qb = ((c & 1) * 2 + ((lane & 15) >> 3)) * 16 + (lane >> 4) * 4;
#pragma unroll
    for (int f = 0; f < 2; ++f)
#pragma unroll
      for (int r = 0; r < 4; ++r) {
        float x = a1[f][r] + bias1;
        x = x / (1.f + expf(-x));
        ushort hh, ll; split_bf(x, hh, ll);
        int idx = buf + ((h * 2 + f) * 2 + (c >> 1)) * 512 + (qb + r) * 8 + (lane & 7);
        HsH[idx] = hh; HsL[idx] = ll;
      }
  };

  {
    f32x4 a1[2] = {{0.f,0.f,0.f,0.f},{0.f,0.f,0.f,0.f}};
    gemm1(0, a1); hswr(0, a1);
  }
#pragma unroll 1
  for (int s = 0; s < 8; ++s) {
    __syncthreads();
    const int buf = (s & 1) * 4096;
#pragma unroll
    for (int ks = 0; ks < 2; ++ks) {
      bf16x8 hh2[2], hl2[2];
#pragma unroll
      for (int f = 0; f < 2; ++f) {
        int hi = buf + ((h * 2 + f) * 2 + ks) * 512 + lane * 8;
        hh2[f] = ld8(&HsH[hi]); hl2[f] = ld8(&HsL[hi]);
      }
#pragma unroll
      for (int g = 0; g < 4; ++g) {
        size_t wt = ((size_t)(c * 4 + g) * 16 + (s * 2 + ks)) * 512 + lane * 8;
        bf16x8 bh = ld8(&W2h[wt]), bl = ld8(&W2l[wt]);
#pragma unroll
        for (int f = 0; f < 2; ++f) {
          acc[f][g] = MFMA(hh2[f], bh, acc[f][g], 0, 0, 0);
          acc[f][g] = MFMA(hl2[f], bh, acc[f][g], 0, 0, 0);
          acc[f][g] = MFMA(hh2[f], bl, acc[f][g], 0, 0, 0);
        }
      }
    }
    if (s < 7) {
      f32x4 a1[2] = {{0.f,0.f,0.f,0.f},{0.f,0.f,0.f,0.f}};
      gemm1(s + 1, a1); hswr(s + 1, a1);
    }
  }
  __syncthreads();  // Hs reads done; trw may reuse the region

  // epilogue: bias2 + branch LN; coalesced via per-wave padded transpose
  float* mytr = trw + w * 1088;
  const int lr = lane >> 2, cb = (lane & 3) * 16;
  const int colL = c * 64 + cb;
  float y[2][16];
#pragma unroll
  for (int f = 0; f < 2; ++f) {
#pragma unroll
    for (int g = 0; g < 4; ++g)
#pragma unroll
      for (int r = 0; r < 4; ++r)
        mytr[((lane >> 4) * 4 + r) * 68 + g * 16 + (lane & 15)] = acc[f][g][r];
    float s1 = 0.f, s2 = 0.f;
#pragma unroll
    for (int i = 0; i < 4; ++i) {
      float4 t = *(const float4*)&mytr[lr * 68 + cb + i * 4];
      float4 bb = *(const float4*)&b2[colL + i * 4];
      y[f][i * 4 + 0] = t.x + bb.x; y[f][i * 4 + 1] = t.y + bb.y;
      y[f][i * 4 + 2] = t.z + bb.z; y[f][i * 4 + 3] = t.w + bb.w;
#pragma unroll
      for (int q2 = 0; q2 < 4; ++q2) { float v = y[f][i * 4 + q2]; s1 += v; s2 += v * v; }
    }
    s1 += __shfl_xor(s1, 1, 64); s2 += __shfl_xor(s2, 1, 64);
    s1 += __shfl_xor(s1, 2, 64); s2 += __shfl_xor(s2, 2, 64);
    if ((lane & 3) == 0) {
      int tl = h * 32 + f * 16 + lr;
      st[tl * 8 + c * 2] = s1; st[tl * 8 + c * 2 + 1] = s2;
    }
  }
  __syncthreads();
#pragma unroll
  for (int f = 0; f < 2; ++f) {
    int tl = h * 32 + f * 16 + lr;
    float s1 = st[tl * 8] + st[tl * 8 + 2] + st[tl * 8 + 4] + st[tl * 8 + 6];
    float s2 = st[tl * 8 + 1] + st[tl * 8 + 3] + st[tl * 8 + 5] + st[tl * 8 + 7];
    float mu = s1 * (1.f / 256.f);
    float rs = rsqrtf(s2 * (1.f / 256.f) - mu * mu + 1e-5f);
    BF8 h0, l0, h1, l1;
#pragma unroll
    for (int i = 0; i < 16; ++i) {
      float z = (y[f][i] - mu) * rs * lw[colL + i] + lb[colL + i];
      ushort hh, ll; split_bf(z, hh, ll);
      if (i < 8) { h0.u[i] = hh; l0.u[i] = ll; } else { h1.u[i - 8] = hh; l1.u[i - 8] = ll; }
    }
    int R = blk * 64 + tl;
    int Cg = br * 256 + colL;
    size_t base = ((size_t)(R >> 4) * 16 + (Cg >> 5)) * 512;
    int q0 = (Cg & 31) >> 3;
    *(bf16x8*)&Fh[base + (q0 * 16 + lr) * 8] = h0.v;
    *(bf16x8*)&Fh[base + ((q0 + 1) * 16 + lr) * 8] = h1.v;
    *(bf16x8*)&Fl[base + (q0 * 16 + lr) * 8] = l0.v;
    *(bf16x8*)&Fl[base + ((q0 + 1) * 16 + lr) * 8] = l1.v;
  }
}

// ---------------------------------------------------------------------------
// KB: M = F @ mg + b; Xc = LN(resid + M, nm); Hb = LN(Xc, ffn_ln).
// ---------------------------------------------------------------------------
__global__ __launch_bounds__(512) void k_mergep(
    const ushort* __restrict__ Fh, const ushort* __restrict__ Fl,
    const ushort* __restrict__ Mh, const ushort* __restrict__ Ml,
    const float* __restrict__ mgb,
    const ushort* __restrict__ Rh, const ushort* __restrict__ Rl,
    const float* __restrict__ nmw, const float* __restrict__ nmb,
    const float* __restrict__ fw, const float* __restrict__ fb,
    ushort* __restrict__ Xch, ushort* __restrict__ Xcl,
    ushort* __restrict__ Hbh, ushort* __restrict__ Hbl) {
  __shared__ float trw[8][1088];
  __shared__ float st[512], stB[512];
  const int tid = threadIdx.x, lane = tid & 63, w = tid >> 6;
  const int h = w >> 2, c = w & 3;
  const int blk = blockIdx.x;

  f32x4 acc[2][4];
#pragma unroll
  for (int f = 0; f < 2; ++f)
#pragma unroll
    for (int g = 0; g < 4; ++g) acc[f][g] = (f32x4){0.f, 0.f, 0.f, 0.f};

#pragma unroll 2
  for (int kt = 0; kt < 16; ++kt) {
    bf16x8 ah[2], al[2];
#pragma unroll
    for (int f = 0; f < 2; ++f) {
      size_t at = ((size_t)(blk * 4 + h * 2 + f) * 16 + kt) * 512 + lane * 8;
      ah[f] = ld8(&Fh[at]); al[f] = ld8(&Fl[at]);
    }
#pragma unroll
    for (int g = 0; g < 4; ++g) {
      size_t wt = ((size_t)(c * 4 + g) * 16 + kt) * 512 + lane * 8;
      bf16x8 bh = ld8(&Mh[wt]), bl = ld8(&Ml[wt]);
#pragma unroll
      for (int f = 0; f < 2; ++f) {
        acc[f][g] = MFMA(ah[f], bh, acc[f][g], 0, 0, 0);
        acc[f][g] = MFMA(al[f], bh, acc[f][g], 0, 0, 0);
        acc[f][g] = MFMA(ah[f], bl, acc[f][g], 0, 0, 0);
      }
    }
  }

  float* mytr = &trw[w][0];
  const int lr = lane >> 2, cb = (lane & 3) * 16;
  const int colL = c * 64 + cb;
  float y[2][16];
#pragma unroll
  for (int f = 0; f < 2; ++f) {
#pragma unroll
    for (int g = 0; g < 4; ++g)
#pragma unroll
      for (int r = 0; r < 4; ++r)
        mytr[((lane >> 4) * 4 + r) * 68 + g * 16 + (lane & 15)] = acc[f][g][r];
    int tl = h * 32 + f * 16 + lr;
    int R = blk * 64 + tl;
    size_t base = ((size_t)(R >> 4) * 8 + (colL >> 5)) * 512;
    int q0 = (colL & 31) >> 3;
    bf16x8 rh0 = ld8(&Rh[base + (q0 * 16 + lr) * 8]);
    bf16x8 rh1 = ld8(&Rh[base + ((q0 + 1) * 16 + lr) * 8]);
    bf16x8 rl0 = ld8(&Rl[base + (q0 * 16 + lr) * 8]);
    bf16x8 rl1 = ld8(&Rl[base + ((q0 + 1) * 16 + lr) * 8]);
    float s1 = 0.f, s2 = 0.f;
#pragma unroll
    for (int i = 0; i < 4; ++i) {
      float4 t = *(const float4*)&mytr[lr * 68 + cb + i * 4];
      float4 bb = *(const float4*)&mgb[colL + i * 4];
      float tv[4] = {t.x + bb.x, t.y + bb.y, t.z + bb.z, t.w + bb.w};
#pragma unroll
      for (int q2 = 0; q2 < 4; ++q2) {
        int ii = i * 4 + q2;
        float rv = (ii < 8) ? join_bf((ushort)rh0[ii], (ushort)rl0[ii])
                            : join_bf((ushort)rh1[ii - 8], (ushort)rl1[ii - 8]);
        float v = tv[q2] + rv;
        y[f][ii] = v; s1 += v; s2 += v * v;
      }
    }
    s1 += __shfl_xor(s1, 1, 64); s2 += __shfl_xor(s2, 1, 64);
    s1 += __shfl_xor(s1, 2, 64); s2 += __shfl_xor(s2, 2, 64);
    if ((lane & 3) == 0) { st[tl * 8 + c * 2] = s1; st[tl * 8 + c * 2 + 1] = s2; }
  }
  __syncthreads();
#pragma unroll
  for (int f = 0; f < 2; ++f) {
    int tl = h * 32 + f * 16 + lr;
    int R = blk * 64 + tl;
    float s1 = st[tl * 8] + st[tl * 8 + 2] + st[tl * 8 + 4] + st[tl * 8 + 6];
    float s2 = st[tl * 8 + 1] + st[tl * 8 + 3] + st[tl * 8 + 5] + st[tl * 8 + 7];
    float mu = s1 * (1.f / 256.f);
    float rs = rsqrtf(s2 * (1.f / 256.f) - mu * mu + 1e-5f);
    BF8 h0, l0, h1, l1;
    float t1 = 0.f, t2 = 0.f;
#pragma unroll
    for (int i = 0; i < 16; ++i) {
      float x = (y[f][i] - mu) * rs * nmw[colL + i] + nmb[colL + i];
      y[f][i] = x; t1 += x; t2 += x * x;
      ushort hh, ll; split_bf(x, hh, ll);
      if (i < 8) { h0.u[i] = hh; l0.u[i] = ll; } else { h1.u[i - 8] = hh; l1.u[i - 8] = ll; }
    }
    size_t base = ((size_t)(R >> 4) * 8 + (colL >> 5)) * 512;
    int q0 = (colL & 31) >> 3;
    *(bf16x8*)&Xch[base + (q0 * 16 + lr) * 8] = h0.v;
    *(bf16x8*)&Xch[base + ((q0 + 1) * 16 + lr) * 8] = h1.v;
    *(bf16x8*)&Xcl[base + (q0 * 16 + lr) * 8] = l0.v;
    *(bf16x8*)&Xcl[base + ((q0 + 1) * 16 + lr) * 8] = l1.v;
    t1 += __shfl_xor(t1, 1, 64); t2 += __shfl_xor(t2, 1, 64);
    t1 += __shfl_xor(t1, 2, 64); t2 += __shfl_xor(t2, 2, 64);
    if ((lane & 3) == 0) { stB[tl * 8 + c * 2] = t1; stB[tl * 8 + c * 2 + 1] = t2; }
  }
  __syncthreads();
#pragma unroll
  for (int f = 0; f < 2; ++f) {
    int tl = h * 32 + f * 16 + lr;
    int R = blk * 64 + tl;
    float s1 = stB[tl * 8] + stB[tl * 8 + 2] + stB[tl * 8 + 4] + stB[tl * 8 + 6];
    float s2 = stB[tl * 8 + 1] + stB[tl * 8 + 3] + stB[tl * 8 + 5] + stB[tl * 8 + 7];
    float mu = s1 * (1.f / 256.f);
    float rs = rsqrtf(s2 * (1.f / 256.f) - mu * mu + 1e-5f);
    BF8 h0, l0, h1, l1;
#pragma unroll
    for (int i = 0; i < 16; ++i) {
      float z = (y[f][i] - mu) * rs * fw[colL + i] + fb[colL + i];
      ushort hh, ll; split_bf(z, hh, ll);
      if (i < 8) { h0.u[i] = hh; l0.u[i] = ll; } else { h1.u[i - 8] = hh; l1.u[i - 8] = ll; }
    }
    size_t base = ((size_t)(R >> 4) * 8 + (colL >> 5)) * 512;
    int q0 = (colL & 31) >> 3;
    *(bf16x8*)&Hbh[base + (q0 * 16 + lr) * 8] = h0.v;
    *(bf16x8*)&Hbh[base + ((q0 + 1) * 16 + lr) * 8] = h1.v;
    *(bf16x8*)&Hbl[base + (q0 * 16 + lr) * 8] = l0.v;
    *(bf16x8*)&Hbl[base + ((q0 + 1) * 16 + lr) * 8] = l1.v;
  }
}

// ---------------------------------------------------------------------------
// KC: out = (Xc + gelu(Hb @ W1 + b1) @ W2 + b2) * mask. 16 slabs of 64.
// ---------------------------------------------------------------------------
template<bool FINAL>
__global__ __launch_bounds__(512) void k_ffn(
    const ushort* __restrict__ Hbh, const ushort* __restrict__ Hbl,
    const ushort* __restrict__ W1h, const ushort* __restrict__ W1l,
    const float* __restrict__ b1,
    const ushort* __restrict__ W2h, const ushort* __restrict__ W2l,
    const float* __restrict__ b2,
    const ushort* __restrict__ Xch, const ushort* __restrict__ Xcl,
    const float* __restrict__ keep,
    float* __restrict__ outf, ushort* __restrict__ Oh, ushort* __restrict__ Ol) {
  __shared__ __align__(16) char lraw[36864];
  ushort* HsH = (ushort*)lraw;
  ushort* HsL = (ushort*)(lraw + 16384);
  float* trw = (float*)lraw;

  const int tid = threadIdx.x, lane = tid & 63, w = tid >> 6;
  const int h = w >> 2, c = w & 3;
  const int blk = blockIdx.x;

  f32x4 acc[2][4];
#pragma unroll
  for (int f = 0; f < 2; ++f)
#pragma unroll
    for (int g = 0; g < 4; ++g) acc[f][g] = (f32x4){0.f, 0.f, 0.f, 0.f};

  auto gemm1 = [&](int s, f32x4* a1) {
#pragma unroll 4
    for (int kt = 0; kt < 8; ++kt) {
      size_t wt = ((size_t)(s * 4 + c) * 8 + kt) * 512 + lane * 8;
      bf16x8 bh = ld8(&W1h[wt]), bl = ld8(&W1l[wt]);
#pragma unroll
      for (int f = 0; f < 2; ++f) {
        size_t at = ((size_t)(blk * 4 + h * 2 + f) * 8 + kt) * 512 + lane * 8;
        bf16x8 ah = ld8(&Hbh[at]), al = ld8(&Hbl[at]);
        a1[f] = MFMA(ah, bh, a1[f], 0, 0, 0);
        a1[f] = MFMA(al, bh, a1[f], 0, 0, 0);
        a1[f] = MFMA(ah, bl, a1[f], 0, 0, 0);
      }
    }
  };
  auto hswr = [&](int s, f32x4* a1) {
    const int buf = (s & 1) * 4096;
    const float bias1 = b1[s * 64 + c * 16 + (lane & 15)];
    const int qb = ((c & 1) * 2 + ((lane & 15) >> 3)) * 16 + (lane >> 4) * 4;
#pragma unroll
    for (int f = 0; f < 2; ++f)
#pragma unroll
      for (int r = 0; r < 4; ++r) {
        float x = a1[f][r] + bias1;
        x = 0.5f * x * (1.f + erff(x * 0.70710678118654752f));
        ushort hh, ll; split_bf(x, hh, ll);
        int idx = buf + ((h * 2 + f) * 2 + (c >> 1)) * 512 + (qb + r) * 8 + (lane & 7);
        HsH[idx] = hh; HsL[idx] = ll;
      }
  };

  {
    f32x4 a1[2] = {{0.f,0.f,0.f,0.f},{0.f,0.f,0.f,0.f}};
    gemm1(0, a1); hswr(0, a1);
  }
#pragma unroll 1
  for (int s = 0; s < 16; ++s) {
    __syncthreads();
    const int buf = (s & 1) * 4096;
#pragma unroll
    for (int ks = 0; ks < 2; ++ks) {
      bf16x8 hh2[2], hl2[2];
#pragma unroll
      for (int f = 0; f < 2; ++f) {
        int hi = buf + ((h * 2 + f) * 2 + ks) * 512 + lane * 8;
        hh2[f] = ld8(&HsH[hi]); hl2[f] = ld8(&HsL[hi]);
      }
#pragma unroll
      for (int g = 0; g < 4; ++g) {
        size_t wt = ((size_t)(c * 4 + g) * 32 + (s * 2 + ks)) * 512 + lane * 8;
        bf16x8 bh = ld8(&W2h[wt]), bl = ld8(&W2l[wt]);
#pragma unroll
        for (int f = 0; f < 2; ++f) {
          acc[f][g] = MFMA(hh2[f], bh, acc[f][g], 0, 0, 0);
          acc[f][g] = MFMA(hl2[f], bh, acc[f][g], 0, 0, 0);
          acc[f][g] = MFMA(hh2[f], bl, acc[f][g], 0, 0, 0);
        }
      }
    }
    if (s < 15) {
      f32x4 a1[2] = {{0.f,0.f,0.f,0.f},{0.f,0.f,0.f,0.f}};
      gemm1(s + 1, a1); hswr(s + 1, a1);
    }
  }
  __syncthreads();

  float* mytr = trw + w * 1088;
  const int lr = lane >> 2, cb = (lane & 3) * 16;
  const int colL = c * 64 + cb;
#pragma unroll
  for (int f = 0; f < 2; ++f) {
#pragma unroll
    for (int g = 0; g < 4; ++g)
#pragma unroll
      for (int r = 0; r < 4; ++r)
        mytr[((lane >> 4) * 4 + r) * 68 + g * 16 + (lane & 15)] = acc[f][g][r];
    int tl = h * 32 + f * 16 + lr;
    int R = blk * 64 + tl;
    float mk = keep[R];
    size_t base = ((size_t)(R >> 4) * 8 + (colL >> 5)) * 512;
    int q0 = (colL & 31) >> 3;
    bf16x8 rh0 = ld8(&Xch[base + (q0 * 16 + lr) * 8]);
    bf16x8 rh1 = ld8(&Xch[base + ((q0 + 1) * 16 + lr) * 8]);
    bf16x8 rl0 = ld8(&Xcl[base + (q0 * 16 + lr) * 8]);
    bf16x8 rl1 = ld8(&Xcl[base + ((q0 + 1) * 16 + lr) * 8]);
    float z[16];
#pragma unroll
    for (int i = 0; i < 4; ++i) {
      float4 t = *(const float4*)&mytr[lr * 68 + cb + i * 4];
      float4 bb = *(const float4*)&b2[colL + i * 4];
      float tv[4] = {t.x + bb.x, t.y + bb.y, t.z + bb.z, t.w + bb.w};
#pragma unroll
      for (int q2 = 0; q2 < 4; ++q2) {
        int ii = i * 4 + q2;
        float rv = (ii < 8) ? join_bf((ushort)rh0[ii], (ushort)rl0[ii])
                            : join_bf((ushort)rh1[ii - 8], (ushort)rl1[ii - 8]);
        z[ii] = (rv + tv[q2]) * mk;
      }
    }
    if (FINAL) {
#pragma unroll
      for (int i = 0; i < 4; ++i)
        *(float4*)&outf[(size_t)R * 256 + colL + i * 4] = *(const float4*)&z[i * 4];
    } else {
      BF8 h0, l0, h1, l1;
#pragma unroll
      for (int i = 0; i < 16; ++i) {
        ushort hh, ll; split_bf(z[i], hh, ll);
        if (i < 8) { h0.u[i] = hh; l0.u[i] = ll; } else { h1.u[i - 8] = hh; l1.u[i - 8] = ll; }
      }
      *(bf16x8*)&Oh[base + (q0 * 16 + lr) * 8] = h0.v;
      *(bf16x8*)&Oh[base + ((q0 + 1) * 16 + lr) * 8] = h1.v;
      *(bf16x8*)&Ol[base + (q0 * 16 + lr) * 8] = l0.v;
      *(bf16x8*)&Ol[base + ((q0 + 1) * 16 + lr) * 8] = l1.v;
    }
  }
}

// X fp32 row-major [rows][256] -> A-frag hl (nkt=8)
__global__ __launch_bounds__(256) void k_xprep(const float* __restrict__ X,
    ushort* __restrict__ Dh, ushort* __restrict__ Dl) {
  int t = blockIdx.x * 4 + (threadIdx.x >> 6);
  int lane = threadIdx.x & 63;
  int rt = t >> 3, kt = t & 7;
  const float* sp = X + (size_t)(rt * 16 + (lane & 15)) * 256 + kt * 32 + (lane >> 4) * 8;
  float4 a = *(const float4*)sp;
  float4 b = *(const float4*)(sp + 4);
  float xs[8] = {a.x, a.y, a.z, a.w, b.x, b.y, b.z, b.w};
  BF8 h, l;
#pragma unroll
  for (int e = 0; e < 8; ++e) split_bf(xs[e], h.u[e], l.u[e]);
  *(bf16x8*)&Dh[(size_t)t * 512 + lane * 8] = h.v;
  *(bf16x8*)&Dl[(size_t)t * 512 + lane * 8] = l.v;
}

// W fp32 [K][Nout] -> B-frag hl [Nout/16][K/32]
__global__ __launch_bounds__(256) void k_wprep(const float* __restrict__ W,
    ushort* __restrict__ Dh, ushort* __restrict__ Dl, int Nout, int K) {
  int t = blockIdx.x * 4 + (threadIdx.x >> 6);
  int lane = threadIdx.x & 63;
  int nkt = K >> 5;
  int nt = t / nkt, kt = t % nkt;
  int n = nt * 16 + (lane & 15);
  int k0 = kt * 32 + (lane >> 4) * 8;
  BF8 h, l;
#pragma unroll
  for (int e = 0; e < 8; ++e) {
    float x = W[(size_t)(k0 + e) * Nout + n];
    split_bf(x, h.u[e], l.u[e]);
  }
  *(bf16x8*)&Dh[(size_t)t * 512 + lane * 8] = h.v;
  *(bf16x8*)&Dl[(size_t)t * 512 + lane * 8] = l.v;
}

extern "C" void kernel_launch(void* const* d_in, const int* in_sizes, int n_in,
                              void* d_out, int out_size, void* d_ws, size_t ws_size,
                              hipStream_t stream) {
  const float* slots  = (const float*)d_in[0];
  const float* keep   = (const float*)d_in[1];
  const float* fw_w1  = (const float*)d_in[2];
  const float* fw_b1  = (const float*)d_in[3];
  const float* fw_w2  = (const float*)d_in[4];
  const float* fw_b2  = (const float*)d_in[5];
  const float* fw_lnw = (const float*)d_in[6];
  const float* fw_lnb = (const float*)d_in[7];
  const float* bw_w1  = (const float*)d_in[8];
  const float* bw_b1  = (const float*)d_in[9];
  const float* bw_w2  = (const float*)d_in[10];
  const float* bw_b2  = (const float*)d_in[11];
  const float* bw_lnw = (const float*)d_in[12];
  const float* bw_lnb = (const float*)d_in[13];
  const float* mg_w   = (const float*)d_in[14];
  const float* mg_b   = (const float*)d_in[15];
  const float* nm_w   = (const float*)d_in[16];
  const float* nm_b   = (const float*)d_in[17];
  const float* ffn_lnw= (const float*)d_in[18];
  const float* ffn_lnb= (const float*)d_in[19];
  const float* ffn_w1 = (const float*)d_in[20];
  const float* ffn_b1 = (const float*)d_in[21];
  const float* ffn_w2 = (const float*)d_in[22];
  const float* ffn_b2 = (const float*)d_in[23];
  (void)n_in; (void)out_size;

  const int N = in_sizes[0] / 256;
  float* out = (float*)d_out;

  size_t off = 0;
  char* wsb = (char*)d_ws;
  auto allocU = [&](size_t elems) -> ushort* {
    void* p = wsb + off;
    off = (off + elems * 2 + 255) & ~(size_t)255;
    return (ushort*)p;
  };

  struct LayerW {
    ushort *fw1h, *fw1l, *bw1h, *bw1l, *fw2h, *fw2l, *bw2h, *bw2l;
    ushort *mgh, *mgl, *f1h, *f1l, *f2h, *f2l;
  } lw[2];
  for (int L = 0; L < 2; ++L) {
    lw[L].fw1h = allocU(131072); lw[L].fw1l = allocU(131072);
    lw[L].bw1h = allocU(131072); lw[L].bw1l = allocU(131072);
    lw[L].fw2h = allocU(131072); lw[L].fw2l = allocU(131072);
    lw[L].bw2h = allocU(131072); lw[L].bw2l = allocU(131072);
    lw[L].mgh  = allocU(131072); lw[L].mgl  = allocU(131072);
    lw[L].f1h  = allocU(262144); lw[L].f1l  = allocU(262144);
    lw[L].f2h  = allocU(262144); lw[L].f2l  = allocU(262144);
  }

  size_t remain = ws_size > off + 4096 ? ws_size - off - 4096 : 0;
  int chunk = N;
  while ((size_t)chunk * 6144 > remain && chunk > 512) chunk >>= 1;

  ushort* Xfh = allocU((size_t)chunk * 256); ushort* Xfl = allocU((size_t)chunk * 256);
  ushort* Fh  = allocU((size_t)chunk * 512); ushort* Fl  = allocU((size_t)chunk * 512);
  ushort* Xch = allocU((size_t)chunk * 256); ushort* Xcl = allocU((size_t)chunk * 256);
  ushort* Hbh = allocU((size_t)chunk * 256); ushort* Hbl = allocU((size_t)chunk * 256);
  ushort* X2h = allocU((size_t)chunk * 256); ushort* X2l = allocU((size_t)chunk * 256);

  for (int L = 0; L < 2; ++L) {
    k_wprep<<<64, 256, 0, stream>>>(fw_w1 + (size_t)L * 131072, lw[L].fw1h, lw[L].fw1l, 512, 256);
    k_wprep<<<64, 256, 0, stream>>>(bw_w1 + (size_t)L * 131072, lw[L].bw1h, lw[L].bw1l, 512, 256);
    k_wprep<<<64, 256, 0, stream>>>(fw_w2 + (size_t)L * 131072, lw[L].fw2h, lw[L].fw2l, 256, 512);
    k_wprep<<<64, 256, 0, stream>>>(bw_w2 + (size_t)L * 131072, lw[L].bw2h, lw[L].bw2l, 256, 512);
    k_wprep<<<64, 256, 0, stream>>>(mg_w + (size_t)L * 131072, lw[L].mgh, lw[L].mgl, 256, 512);
    k_wprep<<<128, 256, 0, stream>>>(ffn_w1 + (size_t)L * 262144, lw[L].f1h, lw[L].f1l, 1024, 256);
    k_wprep<<<128, 256, 0, stream>>>(ffn_w2 + (size_t)L * 262144, lw[L].f2h, lw[L].f2l, 256, 1024);
  }

  for (int c0 = 0; c0 < N; c0 += chunk) {
    k_xprep<<<(chunk / 16) * 2, 256, 0, stream>>>(slots + (size_t)c0 * 256, Xfh, Xfl);
    const int gx = chunk / 64;
    for (int L = 0; L < 2; ++L) {
      const ushort* Xh = (L == 0) ? Xfh : X2h;
      const ushort* Xl = (L == 0) ? Xfl : X2l;
      k_lin12<<<dim3(gx, 2), 512, 0, stream>>>(
          Xh, Xl,
          lw[L].fw1h, lw[L].fw1l, lw[L].bw1h, lw[L].bw1l,
          lw[L].fw2h, lw[L].fw2l, lw[L].bw2h, lw[L].bw2l,
          fw_b1 + (size_t)L * 512, bw_b1 + (size_t)L * 512,
          fw_b2 + (size_t)L * 256, bw_b2 + (size_t)L * 256,
          fw_lnw + (size_t)L * 256, fw_lnb + (size_t)L * 256,
          bw_lnw + (size_t)L * 256, bw_lnb + (size_t)L * 256,
          Fh, Fl);
      k_mergep<<<gx, 512, 0, stream>>>(
          Fh, Fl, lw[L].mgh, lw[L].mgl, mg_b + (size_t)L * 256,
          Xh, Xl,
          nm_w + (size_t)L * 256, nm_b + (size_t)L * 256,
          ffn_lnw + (size_t)L * 256, ffn_lnb + (size_t)L * 256,
          Xch, Xcl, Hbh, Hbl);
      if (L == 0) {
        k_ffn<false><<<gx, 512, 0, stream>>>(
            Hbh, Hbl, lw[L].f1h, lw[L].f1l, ffn_b1 + (size_t)L * 1024,
            lw[L].f2h, lw[L].f2l, ffn_b2 + (size_t)L * 256,
            Xch, Xcl, keep + c0, nullptr, X2h, X2l);
      } else {
        k_ffn<true><<<gx, 512, 0, stream>>>(
            Hbh, Hbl, lw[L].f1h, lw[L].f1l, ffn_b1 + (size_t)L * 1024,
            lw[L].f2h, lw[L].f2l, ffn_b2 + (size_t)L * 256,
            Xch, Xcl, keep + c0, out + (size_t)c0 * 256, nullptr, nullptr);
      }
    }
  }
}